// Round 1
// baseline (772.723 us; speedup 1.0000x reference)
//
#include <hip/hip_runtime.h>

#define NN      100000
#define MHE     200000
#define EE      2000000
#define H1      400000      // hedge keys (2 types)
#define K2N     200000      // node keys (2 types)
#define NBK1    782         // ceil(H1/512)
#define NBK2    782         // ceil(K2N/256)
#define NCB     1024        // counting blocks
#define CHK     1954        // edges per counting block

typedef unsigned short u16;
typedef unsigned int   u32;
typedef unsigned long long ull;
typedef __attribute__((ext_vector_type(8))) short  s16x8;
typedef __attribute__((ext_vector_type(2))) short  s16x2;
typedef __attribute__((ext_vector_type(4))) float  f32x4;
typedef __attribute__((ext_vector_type(4))) unsigned int u32x4;

__device__ __forceinline__ float bf2f(u16 u) { return __uint_as_float(((u32)u) << 16); }
__device__ __forceinline__ u16 f2bf(float f) {
    u32 u = __float_as_uint(f);
    return (u16)((u + 0x7fffu + ((u >> 16) & 1u)) >> 16);
}
__device__ __forceinline__ float ldv(const void* p, long i, int isf32) {
    return isf32 ? ((const float*)p)[i] : bf2f(((const u16*)p)[i]);
}
__device__ __forceinline__ u16 ldb(const void* p, long i, int isf32) {
    return isf32 ? f2bf(((const float*)p)[i]) : ((const u16*)p)[i];
}
__device__ __forceinline__ void stv(void* p, long i, float v, int isf32) {
    if (isf32) ((float*)p)[i] = v;
    else       ((u16*)p)[i] = f2bf(v);
}

union FragU { s16x8 v; ull q[2]; u16 u[8]; };

__device__ __forceinline__ s16x8 ld8bf(const void* p, long off, int isf32) {
    FragU f;
    if (isf32) {
        const float* fp = (const float*)p + off;
        f32x4 a = *(const f32x4*)fp;
        f32x4 b = *(const f32x4*)(fp + 4);
        f.u[0]=f2bf(a[0]); f.u[1]=f2bf(a[1]); f.u[2]=f2bf(a[2]); f.u[3]=f2bf(a[3]);
        f.u[4]=f2bf(b[0]); f.u[5]=f2bf(b[1]); f.u[6]=f2bf(b[2]); f.u[7]=f2bf(b[3]);
    } else {
        u32x4 w = *(const u32x4*)((const u16*)p + off);
        f.q[0] = ((ull)w[1] << 32) | w[0];
        f.q[1] = ((ull)w[3] << 32) | w[2];
    }
    return f.v;
}

__device__ __forceinline__ float sigm(float x) { return 1.f / (1.f + __expf(-x)); }

// ---- ws layout (4-byte units) ----
// lifetimes: cnts1/cnts2 die at placeK12 -> exb (hop1 output) aliases them.
//            bkt1 dies after hop1        -> aggb (hop2 output) aliases it.
#define OFF_BKT1  0            // u32[2,000,000]; aggb u32[1,600,000] aliases
#define OFF_BKT2  2000000      // u32[2,000,000]
#define OFF_EXB   4000000      // u32[3,200,000]
#define OFF_CNT1  4000000      // int[800,768]   (alias inside EXB)
#define OFF_CNT2  4800768      // int[800,768]   (alias inside EXB)
#define OFF_XB    7200000      // u32[800,000]   xb [NN][8] bf16-pairs
#define OFF_TOT   8000000      // int[NBK1+NBK2 = 1564]
#define OFF_BB1   8001564      // int[NBK1+1]
#define OFF_BB2   8002347      // int[NBK2+1]
#define OFF_BCOMB 8003130      // f32[64]
#define OFF_WIHB  8003194      // u16[12288]
#define OFF_WHHB  8009338      // u16[12288]
#define OFF_WCB   8015482      // u16[1024]
#define OFF_FLAG  8015994      // u32

__global__ void detect_kernel(const u32* __restrict__ xw, u32* __restrict__ flag) {
    __shared__ int cnt;
    if (threadIdx.x == 0) cnt = 0;
    __syncthreads();
    int hits = 0;
    for (int i = threadIdx.x; i < 1024; i += 256) {
        float v = bf2f((u16)(xw[i] & 0xffffu));
        if (!(fabsf(v) < 1e10f)) hits++;
    }
    atomicAdd(&cnt, hits);
    __syncthreads();
    if (threadIdx.x == 0) flag[0] = (cnt >= 16) ? 1u : 0u;
}

#define XBASE 26688
__global__ __launch_bounds__(256) void setup_kernel(
        const void* __restrict__ W_conv, const void* __restrict__ b_conv,
        const void* __restrict__ W_mix,  const void* __restrict__ b_mix,
        const void* __restrict__ W_ih,   const void* __restrict__ W_hh,
        const void* __restrict__ x,
        float* __restrict__ bcomb, u16* __restrict__ Wihb, u16* __restrict__ Whhb,
        u16* __restrict__ Wcb, u32* __restrict__ xb, const u32* __restrict__ flag) {
    int isf = (int)flag[0];
    int gid = blockIdx.x * 256 + threadIdx.x;
    if (gid < 12288) {
        Wihb[gid] = ldb(W_ih, gid, isf);
    } else if (gid < 24576) {
        int i = gid - 12288;
        Whhb[i] = ldb(W_hh, i, isf);
    } else if (gid < 26624) {
        int i = gid - 24576;
        int j = i >> 5, k = i & 31;
        int t0 = k >> 4, kk = k & 15;
        float acc = 0.f;
        for (int c = 0; c < 64; c++)
            acc += ldv(W_conv, (t0 * 16 + kk) * 64 + c, isf) * ldv(W_mix, (t0 * 64 + c) * 64 + j, isf);
        Wcb[i] = f2bf(acc);
    } else if (gid < XBASE) {
        int j = gid - 26624;
        if (j < 64) {
            float acc = ldv(b_mix, j, isf);
            for (int c = 0; c < 128; c++)
                acc += ldv(b_conv, c, isf) * ldv(W_mix, c * 64 + j, isf);
            bcomb[j] = acc;
        }
    } else if (gid < XBASE + NN * 8) {
        int i = gid - XBASE;
        int n = i >> 3, c = i & 7;
        u16 lo = ldb(x, (long)n * 16 + 2 * c, isf);
        u16 hi = ldb(x, (long)n * 16 + 2 * c + 1, isf);
        xb[i] = (u32)lo | ((u32)hi << 16);
    }
}

// fused dual histogram: hedge-key buckets (512 wide) and node-key buckets (256 wide)
__global__ __launch_bounds__(512) void countK12(const int* __restrict__ en, const int* __restrict__ eh,
                                                const int* __restrict__ ea,
                                                int* __restrict__ cnts1, int* __restrict__ cnts2) {
    __shared__ int c1[NBK1];
    __shared__ int c2[NBK2];
    int blk = blockIdx.x, tid = threadIdx.x;
    for (int i = tid; i < NBK1; i += 512) c1[i] = 0;
    for (int i = tid; i < NBK2; i += 512) c2[i] = 0;
    __syncthreads();
    int s = blk * CHK;
    int e = s + CHK < EE ? s + CHK : EE;
    for (int i = s + tid; i < e; i += 512) {
        int t = ea[i];
        atomicAdd(&c1[(t * MHE + eh[i]) >> 9], 1);
        atomicAdd(&c2[(t * NN  + en[i]) >> 8], 1);
    }
    __syncthreads();
    for (int b = tid; b < NBK1; b += 512) cnts1[b * NCB + blk] = c1[b];
    for (int b = tid; b < NBK2; b += 512) cnts2[b * NCB + blk] = c2[b];
}

__global__ __launch_bounds__(256) void scanP1(int* __restrict__ cnts, int* __restrict__ totals) {
    __shared__ int lds[256];
    int g = blockIdx.x, t = threadIdx.x;
    int* base = cnts + (long)g * NCB;
    int v[4]; int s = 0;
    #pragma unroll
    for (int j = 0; j < 4; j++) { v[j] = base[t * 4 + j]; s += v[j]; }
    lds[t] = s;
    __syncthreads();
    for (int d = 1; d < 256; d <<= 1) {
        int tmp = (t >= d) ? lds[t - d] : 0;
        __syncthreads();
        lds[t] += tmp;
        __syncthreads();
    }
    int run = lds[t] - s;
    #pragma unroll
    for (int j = 0; j < 4; j++) { base[t * 4 + j] = run; run += v[j]; }
    if (t == 255) totals[g] = lds[255];
}

// NOTE: NBK1 == NBK2 == 782, so this serves both sorts (launched twice with offsets)
__global__ __launch_bounds__(1024) void scanP2(const int* __restrict__ totals, int* __restrict__ bb) {
    __shared__ int lds[1024];
    int t = threadIdx.x;
    int v = (t < NBK1) ? totals[t] : 0;
    lds[t] = v;
    __syncthreads();
    for (int d = 1; d < 1024; d <<= 1) {
        int tmp = (t >= d) ? lds[t - d] : 0;
        __syncthreads();
        lds[t] += tmp;
        __syncthreads();
    }
    if (t < NBK1) bb[t] = lds[t] - v;
    if (t == NBK1 - 1) bb[NBK1] = lds[t];
}

__global__ __launch_bounds__(256) void scanP3(int* __restrict__ cnts, const int* __restrict__ bb) {
    int g = blockIdx.x, t = threadIdx.x;
    int* base = cnts + (long)g * NCB;
    int add = bb[g];
    #pragma unroll
    for (int j = 0; j < 4; j++) base[t * 4 + j] += add;
}

// fused dual placement: bkt1 (by hedge key, payload local|node) and
// bkt2 (by node key, payload local(8b)|hedge-key(19b))
__global__ __launch_bounds__(1024) void placeK12(const int* __restrict__ en, const int* __restrict__ eh,
                                                 const int* __restrict__ ea,
                                                 const int* __restrict__ cnts1, const int* __restrict__ cnts2,
                                                 u32* __restrict__ bkt1, u32* __restrict__ bkt2) {
    __shared__ int r1[NBK1];
    __shared__ int r2[NBK2];
    int blk = blockIdx.x, tid = threadIdx.x;
    for (int i = tid; i < NBK1; i += 1024) r1[i] = 0;
    for (int i = tid; i < NBK2; i += 1024) r2[i] = 0;
    __syncthreads();
    int s = blk * CHK;
    int e = s + CHK < EE ? s + CHK : EE;
    for (int i = s + tid; i < e; i += 1024) {
        int t = ea[i], n = en[i];
        int k1 = t * MHE + eh[i];
        int b1 = k1 >> 9;
        int s1 = cnts1[b1 * NCB + blk] + atomicAdd(&r1[b1], 1);
        bkt1[s1] = ((u32)(k1 & 511) << 17) | (u32)n;
        int k2 = t * NN + n;
        int b2 = k2 >> 8;
        int s2 = cnts2[b2 * NCB + blk] + atomicAdd(&r2[b2], 1);
        bkt2[s2] = ((u32)(k2 & 255) << 19) | (u32)k1;
    }
}

// hop1: per 512-hedge bucket build ex in LDS (f32 atomics), fold Binv,
// write exb packed-bf16 fully coalesced. NO global atomics.
__global__ __launch_bounds__(1024) void hop1(const u32* __restrict__ bkt1, const int* __restrict__ bb1,
                                             const u32* __restrict__ xb, u32* __restrict__ exb) {
    __shared__ float exl[512 * 16];   // 32 KB
    __shared__ float bd[512];
    int b = blockIdx.x, tid = threadIdx.x;
    for (int i = tid; i < 512 * 16; i += 1024) exl[i] = 0.f;
    if (tid < 512) bd[tid] = 0.f;
    __syncthreads();
    int beg = bb1[b], end = bb1[b + 1];
    int sub = tid & 7, grp = tid >> 3;
    for (int i = beg + grp; i < end; i += 128) {
        u32 p = bkt1[i];
        int l = (int)(p >> 17), n = (int)(p & 0x1FFFFu);
        u32 w = xb[(long)n * 8 + sub];
        atomicAdd(&exl[l * 16 + 2 * sub],     bf2f((u16)(w & 0xffffu)));
        atomicAdd(&exl[l * 16 + 2 * sub + 1], bf2f((u16)(w >> 16)));
        if (sub == 0) atomicAdd(&bd[l], 1.0f);
    }
    __syncthreads();
    long base8 = (long)b * 512 * 8;
    for (int j = tid; j < 512 * 8; j += 1024) {
        int k = j >> 3, c = j & 7;
        if (b * 512 + k < H1) {
            float d = bd[k];
            float inv = d > 0.f ? 1.0f / d : 0.f;
            u16 lo = f2bf(exl[k * 16 + 2 * c]     * inv);
            u16 hi = f2bf(exl[k * 16 + 2 * c + 1] * inv);
            exb[base8 + j] = (u32)lo | ((u32)hi << 16);
        }
    }
}

// hop2: per 256-node-key bucket, GATHER exb rows, accumulate in LDS f32,
// fold Dinv, write aggb (Dinv pre-applied) fully coalesced — full coverage,
// so no memset and no Ddeg array needed. NO global atomics.
__global__ __launch_bounds__(1024) void hop2(const u32* __restrict__ bkt2, const int* __restrict__ bb2,
                                             const u32* __restrict__ exb, u32* __restrict__ aggb) {
    __shared__ float al[256 * 16];    // 16 KB
    __shared__ float dd[256];
    int b = blockIdx.x, tid = threadIdx.x;
    for (int i = tid; i < 256 * 16; i += 1024) al[i] = 0.f;
    if (tid < 256) dd[tid] = 0.f;
    __syncthreads();
    int beg = bb2[b], end = bb2[b + 1];
    int sub = tid & 7, grp = tid >> 3;
    for (int i = beg + grp; i < end; i += 128) {
        u32 p = bkt2[i];
        int l = (int)(p >> 19), k1 = (int)(p & 0x7FFFFu);
        u32 w = exb[(long)k1 * 8 + sub];
        atomicAdd(&al[l * 16 + 2 * sub],     bf2f((u16)(w & 0xffffu)));
        atomicAdd(&al[l * 16 + 2 * sub + 1], bf2f((u16)(w >> 16)));
        if (sub == 0) atomicAdd(&dd[l], 1.0f);
    }
    __syncthreads();
    long base8 = (long)b * 256 * 8;
    for (int j = tid; j < 256 * 8; j += 1024) {
        int k = j >> 3, c = j & 7;
        if (b * 256 + k < K2N) {
            float d = dd[k];
            float inv = d > 0.f ? 1.0f / d : 0.f;
            u16 lo = f2bf(al[k * 16 + 2 * c]     * inv);
            u16 hi = f2bf(al[k * 16 + 2 * c + 1] * inv);
            aggb[base8 + j] = (u32)lo | ((u32)hi << 16);
        }
    }
}

// MFMA epilogue; stage-1 A now loads aggb rows directly (Dinv pre-folded in hop2)
__global__ __launch_bounds__(256) void epilogue(const u32* __restrict__ aggb,
                                                const float* __restrict__ bcomb,
                                                const u16* __restrict__ Wihb,
                                                const u16* __restrict__ Whhb,
                                                const u16* __restrict__ Wcb,
                                                const void* __restrict__ b_ih, const void* __restrict__ b_hh,
                                                const void* __restrict__ h_prev,
                                                const void* __restrict__ W_out, const void* __restrict__ b_out,
                                                void* __restrict__ out,
                                                const u32* __restrict__ flag) {
    __shared__ u16 hA[4][16][72];
    int isf = (int)flag[0];
    int tid = threadIdx.x;
    int w = tid >> 6, lane = tid & 63;
    int cl = lane & 15, q = lane >> 4;
    u16* hAw = &hA[w][0][0];

    float bcj[4], br[4], bz[4], bin_[4], bhn[4], wo0[4], wo1[4], wo2[4];
    #pragma unroll
    for (int c = 0; c < 4; c++) {
        int j = c * 16 + cl;
        bcj[c]  = bcomb[j];
        br[c]   = ldv(b_ih, j, isf)       + ldv(b_hh, j, isf);
        bz[c]   = ldv(b_ih, 64 + j, isf)  + ldv(b_hh, 64 + j, isf);
        bin_[c] = ldv(b_ih, 128 + j, isf);
        bhn[c]  = ldv(b_hh, 128 + j, isf);
        wo0[c]  = ldv(W_out, (long)j * 64 + 0, isf);
        wo1[c]  = ldv(W_out, (long)j * 64 + 1, isf);
        wo2[c]  = ldv(W_out, (long)j * 64 + 2, isf);
    }
    float bo0 = ldv(b_out, 0, isf), bo1 = ldv(b_out, 1, isf), bo2 = ldv(b_out, 2, isf);

    for (int wt = blockIdx.x * 4 + w; wt < NN / 16; wt += gridDim.x * 4) {
        long nb = (long)wt * 16;
        {
            int m = cl;
            int t0 = q >> 1;
            long nidx = nb + m;
            const u32* ap = aggb + ((long)t0 * NN + nidx) * 8 + (q & 1) * 4;
            u32x4 aw = *(const u32x4*)ap;
            FragU fa;
            fa.q[0] = ((ull)aw[1] << 32) | aw[0];
            fa.q[1] = ((ull)aw[3] << 32) | aw[2];
            f32x4 hacc[4];
            #pragma unroll
            for (int c = 0; c < 4; c++) {
                hacc[c] = (f32x4){0.f, 0.f, 0.f, 0.f};
                s16x8 bfr = *(const s16x8*)(Wcb + (c * 16 + cl) * 32 + q * 8);
                hacc[c] = __builtin_amdgcn_mfma_f32_16x16x32_bf16(fa.v, bfr, hacc[c], 0, 0, 0);
            }
            #pragma unroll
            for (int c = 0; c < 4; c++) {
                #pragma unroll
                for (int reg = 0; reg < 4; reg++) {
                    int row = q * 4 + reg;
                    float hv = fmaxf(hacc[c][reg] + bcj[c], 0.f);
                    hAw[row * 72 + c * 16 + cl] = f2bf(hv);
                }
            }
        }
        asm volatile("" ::: "memory");
        int m = cl;
        const u16* hrow = hAw + m * 72;
        FragU ha0, ha1;
        #pragma unroll
        for (int j = 0; j < 8; j++) {
            ha0.u[j] = hrow[q * 8 + j];
            ha1.u[j] = hrow[32 + q * 8 + j];
        }
        s16x8 hp0 = ld8bf(h_prev, (nb + m) * 64 + q * 8, isf);
        s16x8 hp1 = ld8bf(h_prev, (nb + m) * 64 + 32 + q * 8, isf);

        f32x4 accr[4], accz[4], accin[4], acchn[4];
        #pragma unroll
        for (int c = 0; c < 4; c++) {
            accr[c]  = (f32x4){br[c], br[c], br[c], br[c]};
            accz[c]  = (f32x4){bz[c], bz[c], bz[c], bz[c]};
            accin[c] = (f32x4){bin_[c], bin_[c], bin_[c], bin_[c]};
            acchn[c] = (f32x4){bhn[c], bhn[c], bhn[c], bhn[c]};
        }
        #pragma unroll
        for (int s = 0; s < 2; s++) {
            s16x8 hf  = s ? ha1.v : ha0.v;
            s16x8 hpf = s ? hp1 : hp0;
            int ko = s * 32 + q * 8;
            #pragma unroll
            for (int c = 0; c < 4; c++) {
                int rr = c * 16 + cl;
                s16x8 bir  = *(const s16x8*)(Wihb + (long)rr * 64 + ko);
                s16x8 bhr  = *(const s16x8*)(Whhb + (long)rr * 64 + ko);
                s16x8 biz  = *(const s16x8*)(Wihb + (long)(64 + rr) * 64 + ko);
                s16x8 bhz  = *(const s16x8*)(Whhb + (long)(64 + rr) * 64 + ko);
                s16x8 bin2 = *(const s16x8*)(Wihb + (long)(128 + rr) * 64 + ko);
                s16x8 bhn2 = *(const s16x8*)(Whhb + (long)(128 + rr) * 64 + ko);
                accr[c]  = __builtin_amdgcn_mfma_f32_16x16x32_bf16(hf,  bir, accr[c], 0, 0, 0);
                accr[c]  = __builtin_amdgcn_mfma_f32_16x16x32_bf16(hpf, bhr, accr[c], 0, 0, 0);
                accz[c]  = __builtin_amdgcn_mfma_f32_16x16x32_bf16(hf,  biz, accz[c], 0, 0, 0);
                accz[c]  = __builtin_amdgcn_mfma_f32_16x16x32_bf16(hpf, bhz, accz[c], 0, 0, 0);
                accin[c] = __builtin_amdgcn_mfma_f32_16x16x32_bf16(hf,  bin2, accin[c], 0, 0, 0);
                acchn[c] = __builtin_amdgcn_mfma_f32_16x16x32_bf16(hpf, bhn2, acchn[c], 0, 0, 0);
            }
        }
        float p0[4] = {0,0,0,0}, p1[4] = {0,0,0,0}, p2[4] = {0,0,0,0};
        #pragma unroll
        for (int c = 0; c < 4; c++) {
            #pragma unroll
            for (int reg = 0; reg < 4; reg++) {
                float rr = sigm(accr[c][reg]);
                float zz = sigm(accz[c][reg]);
                float ng = tanhf(accin[c][reg] + rr * acchn[c][reg]);
                long n = nb + q * 4 + reg;
                long j = c * 16 + cl;
                float hp = ldv(h_prev, n * 64 + j, isf);
                float hx = (1.f - zz) * ng + zz * hp;
                stv(out, n * 64 + j, hx, isf);
                p0[reg] += hx * wo0[c];
                p1[reg] += hx * wo1[c];
                p2[reg] += hx * wo2[c];
            }
        }
        #pragma unroll
        for (int reg = 0; reg < 4; reg++) {
            #pragma unroll
            for (int off2 = 1; off2 < 16; off2 <<= 1) {
                p0[reg] += __shfl_xor(p0[reg], off2);
                p1[reg] += __shfl_xor(p1[reg], off2);
                p2[reg] += __shfl_xor(p2[reg], off2);
            }
        }
        if (cl == 0) {
            #pragma unroll
            for (int reg = 0; reg < 4; reg++) {
                long n = nb + q * 4 + reg;
                long pb = (long)NN * 64 + n * 3;
                stv(out, pb + 0, p0[reg] + bo0, isf);
                stv(out, pb + 1, p1[reg] + bo1, isf);
                stv(out, pb + 2, p2[reg] + bo2, isf);
            }
        }
    }
}

extern "C" void kernel_launch(void* const* d_in, const int* in_sizes, int n_in,
                              void* d_out, int out_size, void* d_ws, size_t ws_size,
                              hipStream_t stream) {
    const void* x      = d_in[0];
    const void* h_prev = d_in[1];
    const int* en      = (const int*)d_in[2];
    const int* eh      = (const int*)d_in[3];
    const int* ea      = (const int*)d_in[4];
    const void* W_conv = d_in[5];
    const void* b_conv = d_in[6];
    const void* W_mix  = d_in[7];
    const void* b_mix  = d_in[8];
    const void* W_ih   = d_in[9];
    const void* W_hh   = d_in[10];
    const void* b_ih   = d_in[11];
    const void* b_hh   = d_in[12];
    const void* W_out  = d_in[13];
    const void* b_out  = d_in[14];
    void* out          = d_out;

    float* ws    = (float*)d_ws;
    u32* bkt1    = (u32*)(ws + OFF_BKT1);
    u32* bkt2    = (u32*)(ws + OFF_BKT2);
    u32* exb     = (u32*)(ws + OFF_EXB);
    int* cnts1   = (int*)(ws + OFF_CNT1);
    int* cnts2   = (int*)(ws + OFF_CNT2);
    u32* aggb    = (u32*)(ws + OFF_BKT1);   // alias: bkt1 dead after hop1
    u32* xb      = (u32*)(ws + OFF_XB);
    int* totals  = (int*)(ws + OFF_TOT);
    int* bb1     = (int*)(ws + OFF_BB1);
    int* bb2     = (int*)(ws + OFF_BB2);
    float* bcomb = ws + OFF_BCOMB;
    u16* Wihb    = (u16*)(ws + OFF_WIHB);
    u16* Whhb    = (u16*)(ws + OFF_WHHB);
    u16* Wcb     = (u16*)(ws + OFF_WCB);
    u32* flag    = (u32*)(ws + OFF_FLAG);

    detect_kernel<<<1, 256, 0, stream>>>((const u32*)x, flag);
    setup_kernel<<<(XBASE + NN * 8 + 255) / 256, 256, 0, stream>>>(
        W_conv, b_conv, W_mix, b_mix, W_ih, W_hh, x,
        bcomb, Wihb, Whhb, Wcb, xb, flag);
    countK12<<<NCB, 512, 0, stream>>>(en, eh, ea, cnts1, cnts2);
    scanP1<<<NBK1 + NBK2, 256, 0, stream>>>(cnts1, totals);   // cnts2 is contiguous after cnts1
    scanP2<<<1, 1024, 0, stream>>>(totals, bb1);
    scanP2<<<1, 1024, 0, stream>>>(totals + NBK1, bb2);
    scanP3<<<NBK1, 256, 0, stream>>>(cnts1, bb1);
    scanP3<<<NBK2, 256, 0, stream>>>(cnts2, bb2);
    placeK12<<<NCB, 1024, 0, stream>>>(en, eh, ea, cnts1, cnts2, bkt1, bkt2);
    hop1<<<NBK1, 1024, 0, stream>>>(bkt1, bb1, xb, exb);
    hop2<<<NBK2, 1024, 0, stream>>>(bkt2, bb2, exb, aggb);
    epilogue<<<1563, 256, 0, stream>>>(aggb, bcomb, Wihb, Whhb, Wcb,
                                       b_ih, b_hh, h_prev, W_out, b_out, out, flag);
}